// Round 33
// baseline (75.318 us; speedup 1.0000x reference)
//
#include <hip/hip_runtime.h>
#include <math.h>

constexpr int NQ      = 14;
constexpr int NSTATE  = 1 << 14;    // 16384 amps
constexpr int NF4     = NSTATE / 2; // 8192 float4 (amp pair) elements
constexpr int NPARAMS = 140;
constexpr int BATCH   = 128;
constexpr int THREADS = 1024;

__device__ __forceinline__ unsigned int f2bf(float f) {
    union { float f; unsigned int u; } v; v.f = f;
    return (v.u + 0x7FFFu + ((v.u >> 16) & 1u)) >> 16;
}
// float4-index swizzle: XOR bits 3-5 into bits 0-2 (linear involution).
__device__ __forceinline__ int SWZ4(int f) { return f ^ ((f >> 3) & 7); }

// SU(2) pair update: b0 = u*a0 + v*a1 ; b1 = -conj(v)*a0 + conj(u)*a1
__device__ __forceinline__ void u_half2(float& ax, float& ay, float& bx, float& by,
                                        float ur, float ui, float vr, float vi) {
    float a0x = ax, a0y = ay, a1x = bx, a1y = by;
    ax =  ur*a0x - ui*a0y + vr*a1x - vi*a1y;
    ay =  ur*a0y + ui*a0x + vr*a1y + vi*a1x;
    bx = -vr*a0x - vi*a0y + ur*a1x + ui*a1y;
    by = -vr*a0y + vi*a0x + ur*a1y - ui*a1x;
}
__device__ __forceinline__ void crx_half(float& ax, float& ay, float& bx, float& by,
                                         float cr, float sr) {
    float a0x = ax, a0y = ay, a1x = bx, a1y = by;
    ax = cr*a0x + sr*a1y;  ay = cr*a0y - sr*a1x;
    bx = cr*a1x + sr*a0y;  by = cr*a1y - sr*a0x;
}

// gate: type 0 = fused 1q on state bit t; type 1 = CRX control bit c -> target t.
// bit 0 = intra-float4. pb = ABSOLUTE param index.
struct G  { int type, pb, c, t; };
struct P2 { int nb, b0, b1, b2, ng; G g[7]; };

// 31 passes, whole circuit (verified R32: commutation-fused, order-preserving).
constexpr P2 PS[31] = {
    {3,13,12,11, 5, {{0,0,0,13},{0,3,0,12},{0,6,0,11},{1,42,13,12},{1,43,12,11}}},
    {2,11,10,0,  2, {{0,9,0,10},{1,44,11,10}}},
    {3,10,9,8,   4, {{0,12,0,9},{0,15,0,8},{1,45,10,9},{1,46,9,8}}},
    {2,8,7,0,    2, {{0,18,0,7},{1,47,8,7}}},
    {3,7,6,5,    4, {{0,21,0,6},{0,24,0,5},{1,48,7,6},{1,49,6,5}}},
    {2,5,4,0,    2, {{0,27,0,4},{1,50,5,4}}},
    {3,4,3,2,    4, {{0,30,0,3},{0,33,0,2},{1,51,4,3},{1,52,3,2}}},
    {2,2,1,0,    2, {{0,36,0,1},{1,53,2,1}}},
    {1,1,0,0,    2, {{0,39,0,0},{1,54,1,0}}},
    {3,13,2,1,   3, {{1,55,0,13},{1,56,0,1},{1,57,1,2}}},
    {3,4,3,2,    2, {{1,58,2,3},{1,59,3,4}}},
    {3,6,5,4,    2, {{1,60,4,5},{1,61,5,6}}},
    {3,8,7,6,    2, {{1,62,6,7},{1,63,7,8}}},
    {3,10,9,8,   2, {{1,64,8,9},{1,65,9,10}}},
    {3,12,11,10, 2, {{1,66,10,11},{1,67,11,12}}},
    {3,13,12,11, 7, {{1,68,12,13},{1,69,13,0},{0,70,0,13},{0,73,0,12},{0,76,0,11},
                     {1,112,13,12},{1,113,12,11}}},
    {2,11,10,0,  2, {{0,79,0,10},{1,114,11,10}}},
    {3,10,9,8,   4, {{0,82,0,9},{0,85,0,8},{1,115,10,9},{1,116,9,8}}},
    {2,8,7,0,    2, {{0,88,0,7},{1,117,8,7}}},
    {3,7,6,5,    4, {{0,91,0,6},{0,94,0,5},{1,118,7,6},{1,119,6,5}}},
    {2,5,4,0,    2, {{0,97,0,4},{1,120,5,4}}},
    {3,4,3,2,    4, {{0,100,0,3},{0,103,0,2},{1,121,4,3},{1,122,3,2}}},
    {2,2,1,0,    2, {{0,106,0,1},{1,123,2,1}}},
    {1,1,0,0,    2, {{0,109,0,0},{1,124,1,0}}},
    {3,13,2,1,   3, {{1,125,0,13},{1,126,0,1},{1,127,1,2}}},
    {3,4,3,2,    2, {{1,128,2,3},{1,129,3,4}}},
    {3,6,5,4,    2, {{1,130,4,5},{1,131,5,6}}},
    {3,8,7,6,    2, {{1,132,6,7},{1,133,7,8}}},
    {3,10,9,8,   2, {{1,134,8,9},{1,135,9,10}}},
    {3,12,11,10, 2, {{1,136,10,11},{1,137,11,12}}},
    {2,13,12,0,  2, {{1,138,12,13},{1,139,13,0}}},
};

struct Sorted { int v[3]; };
constexpr Sorted sort3(int a, int b, int c) {
    Sorted s{{a, b, c}};
    for (int i = 0; i < 3; ++i)
        for (int j = 0; j < 2; ++j)
            if (s.v[j] > s.v[j+1]) { int t = s.v[j]; s.v[j] = s.v[j+1]; s.v[j+1] = t; }
    return s;
}
constexpr int off4(int m, int nb, int b0, int b1, int b2) {
    const int B[3] = { b0 - 1, b1 - 1, b2 - 1 };
    int off = 0;
    for (int j = 0; j < nb; ++j) off |= ((m >> (nb-1-j)) & 1) << B[j];
    return off;
}
constexpr int locbit(int b, int b0, int b1, int b2, int nb) {
    return (b == b0) ? (1 << (nb-1)) : (b == b1) ? (1 << (nb-2)) : (1 << (nb-3));
}
constexpr int touch_mask(P2 ps) {
    const int VN = 1 << ps.nb;
    int t = 0;
    for (int gi = 0; gi < ps.ng; ++gi) {
        G g = ps.g[gi];
        if (g.type == 0 || g.c == 0) { t = (1 << VN) - 1; break; }
        int cb = locbit(g.c, ps.b0, ps.b1, ps.b2, ps.nb);
        for (int m = 0; m < VN; ++m) if (m & cb) t |= 1 << m;
    }
    return t;
}

template<int PI, int GI, int VN>
__device__ __forceinline__ void apply_g(float4 (&v)[VN],
                                        const float4* gco, const float2* gcx) {
    constexpr P2 ps = PS[PI];
    constexpr G  g  = ps.g[GI];
    if constexpr (g.type == 0) {
        constexpr int gi = (g.pb / 70) * 14 + (g.pb % 70) / 3;   // fused-1q table idx
        const float4 U = gco[gi];
        const float ur = U.x, ui = U.y, vr = U.z, vi = U.w;
        if constexpr (g.t == 0) {
            #pragma unroll
            for (int m = 0; m < VN; ++m)
                u_half2(v[m].x, v[m].y, v[m].z, v[m].w, ur, ui, vr, vi);
        } else {
            constexpr int tb = locbit(g.t, ps.b0, ps.b1, ps.b2, ps.nb);
            #pragma unroll
            for (int m = 0; m < VN; ++m) {
                if (m & tb) continue;
                u_half2(v[m].x, v[m].y, v[m|tb].x, v[m|tb].y, ur, ui, vr, vi);
                u_half2(v[m].z, v[m].w, v[m|tb].z, v[m|tb].w, ur, ui, vr, vi);
            }
        }
    } else {
        constexpr int gi = (g.pb / 70) * 28 + (g.pb % 70) - 42;  // CRX table idx
        const float2 C = gcx[gi];
        const float cr = C.x, sr = C.y;
        if constexpr (g.c == 0) {
            constexpr int tb = locbit(g.t, ps.b0, ps.b1, ps.b2, ps.nb);
            #pragma unroll
            for (int m = 0; m < VN; ++m) {
                if (m & tb) continue;
                crx_half(v[m].z, v[m].w, v[m|tb].z, v[m|tb].w, cr, sr);
            }
        } else if constexpr (g.t == 0) {
            constexpr int cb = locbit(g.c, ps.b0, ps.b1, ps.b2, ps.nb);
            #pragma unroll
            for (int m = 0; m < VN; ++m) {
                if (!(m & cb)) continue;
                crx_half(v[m].x, v[m].y, v[m].z, v[m].w, cr, sr);
            }
        } else {
            constexpr int cb = locbit(g.c, ps.b0, ps.b1, ps.b2, ps.nb);
            constexpr int tb = locbit(g.t, ps.b0, ps.b1, ps.b2, ps.nb);
            #pragma unroll
            for (int m = 0; m < VN; ++m) {
                if (!(m & cb) || (m & tb)) continue;
                crx_half(v[m].x, v[m].y, v[m|tb].x, v[m|tb].y, cr, sr);
                crx_half(v[m].z, v[m].w, v[m|tb].z, v[m|tb].w, cr, sr);
            }
        }
    }
}

template<int PI, int GI, int VN>
__device__ __forceinline__ void apply_chain(float4 (&v)[VN],
                                            const float4* gco, const float2* gcx) {
    if constexpr (GI < PS[PI].ng) {
        apply_g<PI, GI, VN>(v, gco, gcx);
        apply_chain<PI, GI + 1, VN>(v, gco, gcx);
    }
}

template<int PI>
__device__ __forceinline__ void do_pass(float4* st4, const float4* gco,
                                        const float2* gcx, int tid) {
    constexpr P2 ps = PS[PI];
    constexpr int NB  = ps.nb;
    constexpr int VN  = 1 << NB;
    constexpr int GPT = 8 >> NB;
    constexpr int TM  = touch_mask(ps);
    constexpr Sorted S = sort3(ps.b0 - 1, (NB > 1 ? ps.b1 - 1 : 99), (NB > 2 ? ps.b2 - 1 : 99));

    #pragma unroll 1
    for (int h = 0; h < GPT; ++h) {
        int base = tid + (h << 10);
        #pragma unroll
        for (int j = 0; j < NB; ++j) {
            const int m = (1 << S.v[j]) - 1;
            base = ((base & ~m) << 1) | (base & m);
        }
        float4 v[VN];
        #pragma unroll
        for (int m = 0; m < VN; ++m) {
            if (!((TM >> m) & 1)) continue;
            v[m] = st4[SWZ4(base | off4(m, NB, ps.b0, ps.b1, ps.b2))];
        }

        apply_chain<PI, 0, VN>(v, gco, gcx);

        #pragma unroll
        for (int m = 0; m < VN; ++m) {
            if (!((TM >> m) & 1)) continue;
            st4[SWZ4(base | off4(m, NB, ps.b0, ps.b1, ps.b2))] = v[m];
        }
        __builtin_amdgcn_sched_barrier(0);
    }
}

template<int PI>
struct RunPasses {
    static __device__ __forceinline__ void go(float4* st4, const float4* gco,
                                              const float2* gcx, int tid) {
        __syncthreads();
        do_pass<PI>(st4, gco, gcx, tid);
        RunPasses<PI + 1>::go(st4, gco, gcx, tid);
    }
};
template<> struct RunPasses<31> {
    static __device__ __forceinline__ void go(float4*, const float4*, const float2*, int) {}
};

__global__
__attribute__((amdgpu_flat_work_group_size(1024, 1024)))
__attribute__((amdgpu_num_vgpr(128)))
void qsim_kernel(const float* __restrict__ params,
                 unsigned int* __restrict__ out_u32) {
    __shared__ float4 st4[NF4];        // 128 KiB; element f = amps (2f, 2f+1), swizzled
    __shared__ float2 gcs[NPARAMS];    // raw (cos, sin) of half-angles
    __shared__ float4 gco[28];         // fused-1q SU(2) coefficients (u, v)
    __shared__ float2 gcx[56];         // CRX (cos, sin)

    const int b   = blockIdx.x;
    const int tid = threadIdx.x;

    if (tid < NPARAMS) {
        float s, c;
        sincosf(0.5f * params[b * NPARAMS + tid], &s, &c);
        gcs[tid] = make_float2(c, s);
    }
    for (int k = tid; k < NF4; k += THREADS)
        st4[k] = make_float4(k == 0 ? 1.f : 0.f, 0.f, 0.f, 0.f);   // SWZ4(0)=0
    __syncthreads();

    // ---- prologue: gate-coefficient tables (broadcast reads in hot loop) ----
    if (tid < 28) {
        const int pb = (tid / 14) * 70 + (tid % 14) * 3;
        const float cx = gcs[pb].x,   sx = gcs[pb].y;
        const float cy = gcs[pb+1].x, sy = gcs[pb+1].y;
        const float cz = gcs[pb+2].x, sz = gcs[pb+2].y;
        const float m0r = cy*cx, m0i = sy*sx, m1r = -sy*cx, m1i = -cy*sx;
        gco[tid] = make_float4(cz*m0r + sz*m0i, cz*m0i - sz*m0r,
                               cz*m1r + sz*m1i, cz*m1i - sz*m1r);
    } else if (tid < 84) {
        const int j = tid - 28;
        gcx[j] = gcs[(j / 28) * 70 + 42 + (j % 28)];
    }

    RunPasses<0>::go(st4, gco, gcx, tid);   // starts with __syncthreads()
    __syncthreads();

    // ---- epilogue: float4 f -> words 2f (im|re), 2f+1 (im|re); coalesced ----
    uint2* ob = (uint2*)(out_u32 + (size_t)b * NSTATE);
    #pragma unroll
    for (int j = 0; j < 8; ++j) {
        const int f = tid + j * 1024;
        const float4 F = st4[SWZ4(f)];
        uint2 w;
        w.x = f2bf(F.y) | (f2bf(F.x) << 16);   // amp 2f   : low=Im, high=Re
        w.y = f2bf(F.w) | (f2bf(F.z) << 16);   // amp 2f+1
        ob[f] = w;
    }
}

extern "C" void kernel_launch(void* const* d_in, const int* in_sizes, int n_in,
                              void* d_out, int out_size, void* d_ws, size_t ws_size,
                              hipStream_t stream) {
    const float* params = (const float*)d_in[0];
    unsigned int* out = (unsigned int*)d_out;
    qsim_kernel<<<BATCH, THREADS, 0, stream>>>(params, out);
}

// Round 34
// 58.500 us; speedup vs baseline: 1.2875x; 1.2875x over previous
//
#include <hip/hip_runtime.h>
#include <math.h>

constexpr int NQ      = 14;
constexpr int NSTATE  = 1 << 14;    // 16384 amps
constexpr int NF4     = NSTATE / 2; // 8192 float4 (amp pair) elements
constexpr int NPARAMS = 140;
constexpr int BATCH   = 128;
constexpr int THREADS = 1024;

__device__ __forceinline__ unsigned int f2bf(float f) {
    union { float f; unsigned int u; } v; v.f = f;
    return (v.u + 0x7FFFu + ((v.u >> 16) & 1u)) >> 16;
}
// float4-index swizzle: XOR bits 3-5 into bits 0-2 (involution).
__device__ __forceinline__ int SWZ4(int f) { return f ^ ((f >> 3) & 7); }

// SU(2) pair update: b0 = u*a0 + v*a1 ; b1 = -conj(v)*a0 + conj(u)*a1
__device__ __forceinline__ void u_half2(float& ax, float& ay, float& bx, float& by,
                                        float ur, float ui, float vr, float vi) {
    float a0x = ax, a0y = ay, a1x = bx, a1y = by;
    ax =  ur*a0x - ui*a0y + vr*a1x - vi*a1y;
    ay =  ur*a0y + ui*a0x + vr*a1y + vi*a1x;
    bx = -vr*a0x - vi*a0y + ur*a1x + ui*a1y;
    by = -vr*a0y + vi*a0x + ur*a1y - ui*a1x;
}
__device__ __forceinline__ void crx_half(float& ax, float& ay, float& bx, float& by,
                                         float cr, float sr) {
    float a0x = ax, a0y = ay, a1x = bx, a1y = by;
    ax = cr*a0x + sr*a1y;  ay = cr*a0y - sr*a1x;
    bx = cr*a1x + sr*a0y;  by = cr*a1y - sr*a0x;
}

// gate: type 0 = fused 1q on state bit t; type 1 = CRX control bit c -> target t.
// bit 0 = intra-float4. pb = ABSOLUTE param index.
struct G  { int type, pb, c, t; };
struct P2 { int nb, b0, b1, b2, ng; G g[7]; };

// 31 passes, whole circuit (verified R32: commutation-fused, order-preserving).
constexpr P2 PS[31] = {
    {3,13,12,11, 5, {{0,0,0,13},{0,3,0,12},{0,6,0,11},{1,42,13,12},{1,43,12,11}}},
    {2,11,10,0,  2, {{0,9,0,10},{1,44,11,10}}},
    {3,10,9,8,   4, {{0,12,0,9},{0,15,0,8},{1,45,10,9},{1,46,9,8}}},
    {2,8,7,0,    2, {{0,18,0,7},{1,47,8,7}}},
    {3,7,6,5,    4, {{0,21,0,6},{0,24,0,5},{1,48,7,6},{1,49,6,5}}},
    {2,5,4,0,    2, {{0,27,0,4},{1,50,5,4}}},
    {3,4,3,2,    4, {{0,30,0,3},{0,33,0,2},{1,51,4,3},{1,52,3,2}}},
    {2,2,1,0,    2, {{0,36,0,1},{1,53,2,1}}},
    {1,1,0,0,    2, {{0,39,0,0},{1,54,1,0}}},
    {3,13,2,1,   3, {{1,55,0,13},{1,56,0,1},{1,57,1,2}}},
    {3,4,3,2,    2, {{1,58,2,3},{1,59,3,4}}},
    {3,6,5,4,    2, {{1,60,4,5},{1,61,5,6}}},
    {3,8,7,6,    2, {{1,62,6,7},{1,63,7,8}}},
    {3,10,9,8,   2, {{1,64,8,9},{1,65,9,10}}},
    {3,12,11,10, 2, {{1,66,10,11},{1,67,11,12}}},
    {3,13,12,11, 7, {{1,68,12,13},{1,69,13,0},{0,70,0,13},{0,73,0,12},{0,76,0,11},
                     {1,112,13,12},{1,113,12,11}}},
    {2,11,10,0,  2, {{0,79,0,10},{1,114,11,10}}},
    {3,10,9,8,   4, {{0,82,0,9},{0,85,0,8},{1,115,10,9},{1,116,9,8}}},
    {2,8,7,0,    2, {{0,88,0,7},{1,117,8,7}}},
    {3,7,6,5,    4, {{0,91,0,6},{0,94,0,5},{1,118,7,6},{1,119,6,5}}},
    {2,5,4,0,    2, {{0,97,0,4},{1,120,5,4}}},
    {3,4,3,2,    4, {{0,100,0,3},{0,103,0,2},{1,121,4,3},{1,122,3,2}}},
    {2,2,1,0,    2, {{0,106,0,1},{1,123,2,1}}},
    {1,1,0,0,    2, {{0,109,0,0},{1,124,1,0}}},
    {3,13,2,1,   3, {{1,125,0,13},{1,126,0,1},{1,127,1,2}}},
    {3,4,3,2,    2, {{1,128,2,3},{1,129,3,4}}},
    {3,6,5,4,    2, {{1,130,4,5},{1,131,5,6}}},
    {3,8,7,6,    2, {{1,132,6,7},{1,133,7,8}}},
    {3,10,9,8,   2, {{1,134,8,9},{1,135,9,10}}},
    {3,12,11,10, 2, {{1,136,10,11},{1,137,11,12}}},
    {2,13,12,0,  2, {{1,138,12,13},{1,139,13,0}}},
};

struct Sorted { int v[3]; };
constexpr Sorted sort3(int a, int b, int c) {
    Sorted s{{a, b, c}};
    for (int i = 0; i < 3; ++i)
        for (int j = 0; j < 2; ++j)
            if (s.v[j] > s.v[j+1]) { int t = s.v[j]; s.v[j] = s.v[j+1]; s.v[j+1] = t; }
    return s;
}
constexpr int off4(int m, int nb, int b0, int b1, int b2) {
    const int B[3] = { b0 - 1, b1 - 1, b2 - 1 };
    int off = 0;
    for (int j = 0; j < nb; ++j) off |= ((m >> (nb-1-j)) & 1) << B[j];
    return off;
}
constexpr int locbit(int b, int b0, int b1, int b2, int nb) {
    return (b == b0) ? (1 << (nb-1)) : (b == b1) ? (1 << (nb-2)) : (1 << (nb-3));
}
constexpr int touch_mask(P2 ps) {
    const int VN = 1 << ps.nb;
    int t = 0;
    for (int gi = 0; gi < ps.ng; ++gi) {
        G g = ps.g[gi];
        if (g.type == 0 || g.c == 0) { t = (1 << VN) - 1; break; }
        int cb = locbit(g.c, ps.b0, ps.b1, ps.b2, ps.nb);
        for (int m = 0; m < VN; ++m) if (m & cb) t |= 1 << m;
    }
    return t;
}

template<int PI, int GI, int VN>
__device__ __forceinline__ void apply_g(float4 (&v)[VN], const float2* gcs) {
    constexpr P2 ps = PS[PI];
    constexpr G  g  = ps.g[GI];
    if constexpr (g.type == 0) {
        const float2 X = gcs[g.pb], Y = gcs[g.pb+1], Z = gcs[g.pb+2];
        const float cx = X.x, sx = X.y, cy = Y.x, sy = Y.y, cz = Z.x, sz = Z.y;
        const float m0r = cy*cx, m0i = sy*sx, m1r = -sy*cx, m1i = -cy*sx;
        const float ur = cz*m0r + sz*m0i, ui = cz*m0i - sz*m0r;
        const float vr = cz*m1r + sz*m1i, vi = cz*m1i - sz*m1r;
        if constexpr (g.t == 0) {
            #pragma unroll
            for (int m = 0; m < VN; ++m)
                u_half2(v[m].x, v[m].y, v[m].z, v[m].w, ur, ui, vr, vi);
        } else {
            constexpr int tb = locbit(g.t, ps.b0, ps.b1, ps.b2, ps.nb);
            #pragma unroll
            for (int m = 0; m < VN; ++m) {
                if (m & tb) continue;
                u_half2(v[m].x, v[m].y, v[m|tb].x, v[m|tb].y, ur, ui, vr, vi);
                u_half2(v[m].z, v[m].w, v[m|tb].z, v[m|tb].w, ur, ui, vr, vi);
            }
        }
    } else {
        const float2 C = gcs[g.pb];
        const float cr = C.x, sr = C.y;
        if constexpr (g.c == 0) {            // control = bit 0: zw halves only
            constexpr int tb = locbit(g.t, ps.b0, ps.b1, ps.b2, ps.nb);
            #pragma unroll
            for (int m = 0; m < VN; ++m) {
                if (m & tb) continue;
                crx_half(v[m].z, v[m].w, v[m|tb].z, v[m|tb].w, cr, sr);
            }
        } else if constexpr (g.t == 0) {     // target = bit 0: intra-float4
            constexpr int cb = locbit(g.c, ps.b0, ps.b1, ps.b2, ps.nb);
            #pragma unroll
            for (int m = 0; m < VN; ++m) {
                if (!(m & cb)) continue;
                crx_half(v[m].x, v[m].y, v[m].z, v[m].w, cr, sr);
            }
        } else {
            constexpr int cb = locbit(g.c, ps.b0, ps.b1, ps.b2, ps.nb);
            constexpr int tb = locbit(g.t, ps.b0, ps.b1, ps.b2, ps.nb);
            #pragma unroll
            for (int m = 0; m < VN; ++m) {
                if (!(m & cb) || (m & tb)) continue;
                crx_half(v[m].x, v[m].y, v[m|tb].x, v[m|tb].y, cr, sr);
                crx_half(v[m].z, v[m].w, v[m|tb].z, v[m|tb].w, cr, sr);
            }
        }
    }
}

template<int PI, int GI, int VN>
__device__ __forceinline__ void apply_chain(float4 (&v)[VN], const float2* gcs) {
    if constexpr (GI < PS[PI].ng) {
        apply_g<PI, GI, VN>(v, gcs);
        __builtin_amdgcn_sched_barrier(0);   // forbid cross-gate coefficient hoisting
        apply_chain<PI, GI + 1, VN>(v, gcs);
    }
}

template<int PI>
__device__ __forceinline__ void do_pass(float4* st4, const float2* gcs, int tid) {
    constexpr P2 ps = PS[PI];
    constexpr int NB  = ps.nb;
    constexpr int VN  = 1 << NB;
    constexpr int GPT = 8 >> NB;
    constexpr int TM  = touch_mask(ps);
    constexpr Sorted S = sort3(ps.b0 - 1, (NB > 1 ? ps.b1 - 1 : 99), (NB > 2 ? ps.b2 - 1 : 99));

    #pragma unroll
    for (int h = 0; h < GPT; ++h) {
        int base = tid + (h << 10);
        #pragma unroll
        for (int j = 0; j < NB; ++j) {           // insert 0 at sorted float4-bits
            const int m = (1 << S.v[j]) - 1;
            base = ((base & ~m) << 1) | (base & m);
        }
        float4 v[VN];
        #pragma unroll
        for (int m = 0; m < VN; ++m) {
            if (!((TM >> m) & 1)) continue;       // untouched: skip load
            v[m] = st4[SWZ4(base | off4(m, NB, ps.b0, ps.b1, ps.b2))];
        }

        apply_chain<PI, 0, VN>(v, gcs);

        #pragma unroll
        for (int m = 0; m < VN; ++m) {
            if (!((TM >> m) & 1)) continue;       // untouched: skip store
            st4[SWZ4(base | off4(m, NB, ps.b0, ps.b1, ps.b2))] = v[m];
        }
        __builtin_amdgcn_sched_barrier(0);
    }
}

template<int PI>
struct RunPasses {
    static __device__ __forceinline__ void go(float4* st4, const float2* gcs, int tid) {
        __syncthreads();
        do_pass<PI>(st4, gcs, tid);
        RunPasses<PI + 1>::go(st4, gcs, tid);
    }
};
template<> struct RunPasses<31> {
    static __device__ __forceinline__ void go(float4*, const float2*, int) {}
};

__global__
__attribute__((amdgpu_flat_work_group_size(1024, 1024)))
void qsim_kernel(const float* __restrict__ params,
                 unsigned int* __restrict__ out_u32) {
    __shared__ float4 st4[NF4];        // 128 KiB; element f = amps (2f, 2f+1), swizzled
    __shared__ float2 gcs[NPARAMS];

    const int b   = blockIdx.x;
    const int tid = threadIdx.x;

    if (tid < NPARAMS) {
        float s, c;
        sincosf(0.5f * params[b * NPARAMS + tid], &s, &c);
        gcs[tid] = make_float2(c, s);
    }
    for (int k = tid; k < NF4; k += THREADS)
        st4[k] = make_float4(k == 0 ? 1.f : 0.f, 0.f, 0.f, 0.f);   // SWZ4(0)=0

    RunPasses<0>::go(st4, gcs, tid);   // each pass starts with __syncthreads()
    __syncthreads();

    // ---- epilogue: float4 f -> words 2f (im|re), 2f+1 (im|re); coalesced ----
    uint2* ob = (uint2*)(out_u32 + (size_t)b * NSTATE);
    #pragma unroll
    for (int j = 0; j < 8; ++j) {
        const int f = tid + j * 1024;
        const float4 F = st4[SWZ4(f)];
        uint2 w;
        w.x = f2bf(F.y) | (f2bf(F.x) << 16);   // amp 2f   : low=Im, high=Re
        w.y = f2bf(F.w) | (f2bf(F.z) << 16);   // amp 2f+1
        ob[f] = w;
    }
}

extern "C" void kernel_launch(void* const* d_in, const int* in_sizes, int n_in,
                              void* d_out, int out_size, void* d_ws, size_t ws_size,
                              hipStream_t stream) {
    const float* params = (const float*)d_in[0];
    unsigned int* out = (unsigned int*)d_out;
    qsim_kernel<<<BATCH, THREADS, 0, stream>>>(params, out);
}